// Round 8
// baseline (192.948 us; speedup 1.0000x reference)
//
#include <hip/hip_runtime.h>

#define N_NODES  100000
#define N_EDGES  1600000
#define HIDDEN   128
#define N_GRAPHS 2048
#define VOCAB    28
#define NB       512        // dst buckets of 196 nodes (512*196 = 100352)
#define NPB      196        // nodes per bucket
#define CAP      3600       // per-bucket capacity (E=3136, sigma~56 -> +8.3σ); 16B-aligned
#define NBIN     512        // binning blocks
#define I4PB     784        // int4 edge-loads per binning block (784*4 = 3136 edges)
#define CSTR     29         // lcnt stride (gcd(29,32)=1 -> conflict-free)
#define MAGIC196 1402438302ULL  // b=(dst*M)>>38, exact for dst<2.8e5 (r6-proven)

// ---------------------------------------------------------------------------
// k_init: blocks 0..9: zero y_hat(2048)+gcursor(512); blocks 10..23:
// T = embed @ w1_0  [28,128] (3584 = 14*256).
// ---------------------------------------------------------------------------
__global__ __launch_bounds__(256) void k_init(float* __restrict__ out,
                                              int* __restrict__ gcursor,
                                              const float* __restrict__ embed,
                                              const float* __restrict__ w1_0,
                                              float* __restrict__ T) {
    const int bid = blockIdx.x, tid = threadIdx.x;
    if (bid < 10) {
        int i = bid * 256 + tid;
        if (i < N_GRAPHS) out[i] = 0.0f;
        else if (i < N_GRAPHS + NB) gcursor[i - N_GRAPHS] = 0;
    } else {
        int g = (bid - 10) * 256 + tid;            // < 3584
        int i = g >> 7, j = g & 127;
        float s = 0.f;
#pragma unroll 8
        for (int k = 0; k < HIDDEN; ++k)
            s += embed[i * HIDDEN + k] * w1_0[k * HIDDEN + j];
        T[g] = s;
    }
}

// ---------------------------------------------------------------------------
// k_bin: blocks [0,512): scan-free direct-scatter multisplit, int4 edge loads.
//   packed: dl<<22 | vix<<17 | src
// blocks [512,516): EW = T @ w2_0 ; block 516: bc0/wc1/bc1 folds.
// ---------------------------------------------------------------------------
__global__ __launch_bounds__(1024) void k_bin(const int* __restrict__ esrc,
                                              const int* __restrict__ edst,
                                              const int* __restrict__ x_idx,
                                              unsigned* __restrict__ binned,
                                              int* __restrict__ gcursor,
                                              const float* __restrict__ T,
                                              const float* __restrict__ w2_0,
                                              const float* __restrict__ b1_0,
                                              const float* __restrict__ b2_0,
                                              const float* __restrict__ w1_1,
                                              const float* __restrict__ b1_1,
                                              const float* __restrict__ w2_1,
                                              const float* __restrict__ b2_1,
                                              float* __restrict__ EW,
                                              float* __restrict__ bc0,
                                              float* __restrict__ wc1,
                                              float* __restrict__ bc1) {
    const int tid = threadIdx.x;
    const int bid = blockIdx.x;

    if (bid >= NBIN) {
        if (bid < NBIN + 4) {                       // EW = T @ w2_0 [28,128]
            int g = (bid - NBIN) * 1024 + tid;
            if (g < VOCAB * HIDDEN) {
                int i = g >> 7, j = g & 127;
                float s = 0.f;
#pragma unroll 8
                for (int k = 0; k < HIDDEN; ++k)
                    s += T[i * HIDDEN + k] * w2_0[k * HIDDEN + j];
                EW[g] = s;
            }
        } else {                                    // bias / wc1 folds
            if (tid < 128) {
                float s = 0.f;
#pragma unroll 8
                for (int k = 0; k < HIDDEN; ++k)
                    s += b1_0[k] * w2_0[k * HIDDEN + tid];
                bc0[tid] = s + b2_0[tid];
                if (tid == 0) {
                    float q = 0.f;
                    for (int k = 0; k < HIDDEN; ++k) q += b1_1[k] * w2_1[k];
                    bc1[0] = q + b2_1[0];
                }
            } else if (tid < 256) {
                int i = tid - 128;
                float s = 0.f;
#pragma unroll 8
                for (int k = 0; k < HIDDEN; ++k)
                    s += w1_1[i * HIDDEN + k] * w2_1[k];
                wc1[i] = s;
            }
        }
        return;
    }

    __shared__ int hist[NB];
    __shared__ int lcur[NB];
    __shared__ int gbase[NB];

    if (tid < NB) { hist[tid] = 0; lcur[tid] = 0; }
    __syncthreads();

    unsigned mypk[4];
    short    myb[4];
    myb[0] = myb[1] = myb[2] = myb[3] = -1;

    if (tid < I4PB) {
        int i4 = bid * I4PB + tid;
        int e  = i4 << 2;
        if (e < N_EDGES) {                           // 1.6M % 4 == 0: all-or-none
            int4 s4 = reinterpret_cast<const int4*>(esrc)[i4];
            int4 d4 = reinterpret_cast<const int4*>(edst)[i4];
            int srcs[4] = { s4.x, s4.y, s4.z, s4.w };
            int dsts[4] = { d4.x, d4.y, d4.z, d4.w };
#pragma unroll
            for (int j = 0; j < 4; ++j) {
                int dst = dsts[j];
                int src = srcs[j];
                int b   = (int)(((unsigned long long)dst * MAGIC196) >> 38);
                int dl  = dst - b * NPB;             // 0..195 (8 bits)
                int vix = x_idx[src];                // 0..27  (5 bits)
                mypk[j] = ((unsigned)dl << 22) | ((unsigned)vix << 17) | (unsigned)src;
                myb[j]  = (short)b;
                atomicAdd(&hist[b], 1);
            }
        }
    }
    __syncthreads();

    if (tid < NB) {
        int v = hist[tid];
        gbase[tid] = (v > 0) ? atomicAdd(&gcursor[tid], v) : 0;
    }
    __syncthreads();

#pragma unroll
    for (int j = 0; j < 4; ++j) {
        if (myb[j] >= 0) {
            int b  = myb[j];
            int lr = atomicAdd(&lcur[b], 1);
            binned[(size_t)b * CAP + gbase[b] + lr] = mypk[j];
        }
    }
}

// ---------------------------------------------------------------------------
// k_layerC: one block (1024 thr) per bucket of 196 nodes; ~26.8 KB LDS ->
// 2 blocks/CU.
//   1) uint4 scan of bucket edges -> LDS vocab histogram (stride-29)
//   2) 4-way split epilogue: thread (q=tid>>8, nl=tid&255) computes f4 in
//      [8q,8q+8) for node nl; partials reduced via LDS. EW loads wave-uniform
//      (q flips at wave boundaries).
//   dvec[n] = dot(relu(sum_v cf_v*EW[v] + bc0), wc1)
// ---------------------------------------------------------------------------
__global__ __launch_bounds__(1024) void k_layerC(const unsigned* __restrict__ binned,
                                                 const int* __restrict__ gcursor,
                                                 const int* __restrict__ x_idx,
                                                 const float* __restrict__ EW,
                                                 const float* __restrict__ bc0,
                                                 const float* __restrict__ wc1,
                                                 const float* __restrict__ eps0,
                                                 float* __restrict__ dvec) {
    __shared__ int   lcnt[NPB * CSTR];    // 22.7 KB
    __shared__ float part[1024];          //  4.0 KB

    const int tid = threadIdx.x;
    const int b   = blockIdx.x;

    for (int i = tid; i < NPB * CSTR; i += 1024) lcnt[i] = 0;
    __syncthreads();

    const int cnt = gcursor[b];
    const unsigned* bp = binned + (size_t)b * CAP;
    const uint4* bp4 = reinterpret_cast<const uint4*>(bp);
    const int cnt4 = cnt >> 2;
    for (int i = tid; i < cnt4; i += 1024) {
        uint4 p = bp4[i];
        atomicAdd(&lcnt[(p.x >> 22) * CSTR + ((p.x >> 17) & 31)], 1);
        atomicAdd(&lcnt[(p.y >> 22) * CSTR + ((p.y >> 17) & 31)], 1);
        atomicAdd(&lcnt[(p.z >> 22) * CSTR + ((p.z >> 17) & 31)], 1);
        atomicAdd(&lcnt[(p.w >> 22) * CSTR + ((p.w >> 17) & 31)], 1);
    }
    for (int i = (cnt4 << 2) + tid; i < cnt; i += 1024) {   // tail < 4
        unsigned pk = bp[i];
        atomicAdd(&lcnt[(pk >> 22) * CSTR + ((pk >> 17) & 31)], 1);
    }
    __syncthreads();

    const int q  = tid >> 8;        // 0..3: feature quarter
    const int nl = tid & 255;       // node-local
    const int n  = b * NPB + nl;
    const bool active = (nl < NPB);
    const bool valid  = active && (n < N_NODES);

    float dacc = 0.f;
    if (active) {
        const int xi  = valid ? x_idx[n] : 0;
        const float s = 1.0f + eps0[0];

        float cf[VOCAB];
#pragma unroll
        for (int v = 0; v < VOCAB; ++v)
            cf[v] = (float)lcnt[nl * CSTR + v] + ((v == xi) ? s : 0.0f);

        const float4* EW4 = reinterpret_cast<const float4*>(EW);  // uniform
        const float4* b04 = reinterpret_cast<const float4*>(bc0);
        const float4* w14 = reinterpret_cast<const float4*>(wc1);

#pragma unroll 1
        for (int f4 = q * 8; f4 < q * 8 + 8; ++f4) {
            float4 a = b04[f4];
#pragma unroll
            for (int v = 0; v < VOCAB; ++v) {
                float4 e = EW4[v * 32 + f4];
                a.x += cf[v] * e.x;
                a.y += cf[v] * e.y;
                a.z += cf[v] * e.z;
                a.w += cf[v] * e.w;
            }
            float4 w = w14[f4];
            dacc += fmaxf(a.x, 0.f) * w.x + fmaxf(a.y, 0.f) * w.y
                  + fmaxf(a.z, 0.f) * w.z + fmaxf(a.w, 0.f) * w.w;
        }
    }
    part[tid] = dacc;               // layout [q*256 + nl]
    __syncthreads();

    if (q == 0 && valid)
        dvec[n] = part[nl] + part[256 + nl] + part[512 + nl] + part[768 + nl];
}

// ---------------------------------------------------------------------------
// k_B2: one block (1024 thr) per bucket; ~9 KB LDS. uint4 scan; layer-1
// aggregation via LDS float atomics on racc[196] from L2-resident dvec
// gathers. Fused x write + graph segment-sum (batch sorted). OOB-clamped.
// ---------------------------------------------------------------------------
__global__ __launch_bounds__(1024) void k_B2(const unsigned* __restrict__ binned,
                                             const int* __restrict__ gcursor,
                                             const float* __restrict__ dvec,
                                             const int* __restrict__ batch,
                                             const float* __restrict__ eps1,
                                             const float* __restrict__ bc1,
                                             float* __restrict__ out) {
    __shared__ float racc[NPB];
    __shared__ float gacc[N_GRAPHS];

    const int tid = threadIdx.x;
    const int b   = blockIdx.x;
    const int n0  = b * NPB;
    const int nfirst = min(n0, N_NODES - 1);             // bucket 511: n0 >= N
    const int nlast  = min(n0 + NPB - 1, N_NODES - 1);

    if (tid < NPB) racc[tid] = 0.f;
    const int g0 = batch[nfirst];
    const int g1 = batch[nlast];
    for (int g = g0 + tid; g <= g1; g += 1024) gacc[g] = 0.f;
    __syncthreads();

    const int cnt = gcursor[b];
    const unsigned* bp = binned + (size_t)b * CAP;
    const uint4* bp4 = reinterpret_cast<const uint4*>(bp);
    const int cnt4 = cnt >> 2;
    for (int i = tid; i < cnt4; i += 1024) {
        uint4 p = bp4[i];
        atomicAdd(&racc[p.x >> 22], dvec[p.x & 0x1FFFFu]);
        atomicAdd(&racc[p.y >> 22], dvec[p.y & 0x1FFFFu]);
        atomicAdd(&racc[p.z >> 22], dvec[p.z & 0x1FFFFu]);
        atomicAdd(&racc[p.w >> 22], dvec[p.w & 0x1FFFFu]);
    }
    for (int i = (cnt4 << 2) + tid; i < cnt; i += 1024) {   // tail < 4
        unsigned pk = bp[i];
        atomicAdd(&racc[pk >> 22], dvec[pk & 0x1FFFFu]);
    }
    __syncthreads();

    int n = n0 + tid;
    if (tid < NPB && n < N_NODES) {
        float r = (1.0f + eps1[0]) * dvec[n] + racc[tid] + bc1[0];
        out[N_GRAPHS + n] = r;
        atomicAdd(&gacc[batch[n]], r);
    }
    __syncthreads();
    for (int g = g0 + tid; g <= g1; g += 1024) {
        float v = gacc[g];
        if (v != 0.f) atomicAdd(&out[g], v);
    }
}

// ---------------------------------------------------------------------------
extern "C" void kernel_launch(void* const* d_in, const int* in_sizes, int n_in,
                              void* d_out, int out_size, void* d_ws, size_t ws_size,
                              hipStream_t stream) {
    const int*   x_idx = (const int*)d_in[0];
    const int*   esrc  = (const int*)d_in[1];
    const int*   edst  = (const int*)d_in[2];
    const int*   batch = (const int*)d_in[3];
    const float* embed = (const float*)d_in[4];
    const float* eps0  = (const float*)d_in[5];
    const float* w1_0  = (const float*)d_in[6];
    const float* b1_0  = (const float*)d_in[7];
    const float* w2_0  = (const float*)d_in[8];
    const float* b2_0  = (const float*)d_in[9];
    const float* eps1  = (const float*)d_in[10];
    const float* w1_1  = (const float*)d_in[11];
    const float* b1_1  = (const float*)d_in[12];
    const float* w2_1  = (const float*)d_in[13];
    const float* b2_1  = (const float*)d_in[14];

    float* out = (float*)d_out;

    // ws: [gcursor(512) | binned(NB*CAP) | dvec(100352) | T | EW | bc0 | wc1 | bc1]
    int*      gcursor = (int*)d_ws;                           // 512
    unsigned* binned  = (unsigned*)(gcursor + 512);           // 512*3600
    float*    dvec    = (float*)(binned + (size_t)NB * CAP);  // 100352
    float*    T       = dvec + 100352;                        // 3584
    float*    EW      = T + VOCAB * HIDDEN;                   // 3584
    float*    bc0     = EW + VOCAB * HIDDEN;                  // 128
    float*    wc1     = bc0 + HIDDEN;                         // 128
    float*    bc1     = wc1 + HIDDEN;                         // 1

    // zero y_hat+gcursor; T = embed @ w1_0
    k_init<<<24, 256, 0, stream>>>(out, gcursor, embed, w1_0, T);

    // bin edges (int4 loads, 2 blocks/CU); EW/bias folds in extra blocks
    k_bin<<<NBIN + 5, 1024, 0, stream>>>(esrc, edst, x_idx, binned, gcursor,
                                         T, w2_0, b1_0, b2_0,
                                         w1_1, b1_1, w2_1, b2_1,
                                         EW, bc0, wc1, bc1);

    // layer 0 (+dot wc1): uint4 scan + 4-way split epilogue
    k_layerC<<<NB, 1024, 0, stream>>>(binned, gcursor, x_idx, EW, bc0, wc1,
                                      eps0, dvec);

    // layer 1 aggregation + fused outputs: uint4 scan
    k_B2<<<NB, 1024, 0, stream>>>(binned, gcursor, dvec, batch, eps1, bc1, out);
}

// Round 9
// 160.057 us; speedup vs baseline: 1.2055x; 1.2055x over previous
//
#include <hip/hip_runtime.h>

#define N_NODES  100000
#define N_EDGES  1600000
#define HIDDEN   128
#define N_GRAPHS 2048
#define VOCAB    28
#define NB       512        // dst buckets of 196 nodes (512*196 = 100352)
#define NPB      196        // nodes per bucket
#define CAP      3600       // per-bucket capacity (E=3136, sigma~56 -> +8.3σ); 16B-aligned
#define NBIN     512        // binning blocks
#define I4PB     784        // int4 edge-loads per binning block (784*4 = 3136 edges)
#define CSTR     29         // lcnt stride (gcd(29,32)=1 -> conflict-free)
#define MAGIC196 1402438302ULL  // b=(dst*M)>>38, exact for dst<2.8e5 (r6-proven)

// ---------------------------------------------------------------------------
// k_init: blocks 0..9: zero y_hat(2048)+gcursor(512); blocks 10..23:
// T = embed @ w1_0  [28,128] (3584 = 14*256).
// ---------------------------------------------------------------------------
__global__ __launch_bounds__(256) void k_init(float* __restrict__ out,
                                              int* __restrict__ gcursor,
                                              const float* __restrict__ embed,
                                              const float* __restrict__ w1_0,
                                              float* __restrict__ T) {
    const int bid = blockIdx.x, tid = threadIdx.x;
    if (bid < 10) {
        int i = bid * 256 + tid;
        if (i < N_GRAPHS) out[i] = 0.0f;
        else if (i < N_GRAPHS + NB) gcursor[i - N_GRAPHS] = 0;
    } else {
        int g = (bid - 10) * 256 + tid;            // < 3584
        int i = g >> 7, j = g & 127;
        float s = 0.f;
#pragma unroll 8
        for (int k = 0; k < HIDDEN; ++k)
            s += embed[i * HIDDEN + k] * w1_0[k * HIDDEN + j];
        T[g] = s;
    }
}

// ---------------------------------------------------------------------------
// k_bin: blocks [0,512): scan-free direct-scatter multisplit, int4 edge loads.
//   packed: dl<<22 | vix<<17 | src
// blocks [512,516): EW = T @ w2_0 ; block 516: bc0/wc1/bc1 folds.
// ---------------------------------------------------------------------------
__global__ __launch_bounds__(1024) void k_bin(const int* __restrict__ esrc,
                                              const int* __restrict__ edst,
                                              const int* __restrict__ x_idx,
                                              unsigned* __restrict__ binned,
                                              int* __restrict__ gcursor,
                                              const float* __restrict__ T,
                                              const float* __restrict__ w2_0,
                                              const float* __restrict__ b1_0,
                                              const float* __restrict__ b2_0,
                                              const float* __restrict__ w1_1,
                                              const float* __restrict__ b1_1,
                                              const float* __restrict__ w2_1,
                                              const float* __restrict__ b2_1,
                                              float* __restrict__ EW,
                                              float* __restrict__ bc0,
                                              float* __restrict__ wc1,
                                              float* __restrict__ bc1) {
    const int tid = threadIdx.x;
    const int bid = blockIdx.x;

    if (bid >= NBIN) {
        if (bid < NBIN + 4) {                       // EW = T @ w2_0 [28,128]
            int g = (bid - NBIN) * 1024 + tid;
            if (g < VOCAB * HIDDEN) {
                int i = g >> 7, j = g & 127;
                float s = 0.f;
#pragma unroll 8
                for (int k = 0; k < HIDDEN; ++k)
                    s += T[i * HIDDEN + k] * w2_0[k * HIDDEN + j];
                EW[g] = s;
            }
        } else {                                    // bias / wc1 folds
            if (tid < 128) {
                float s = 0.f;
#pragma unroll 8
                for (int k = 0; k < HIDDEN; ++k)
                    s += b1_0[k] * w2_0[k * HIDDEN + tid];
                bc0[tid] = s + b2_0[tid];
                if (tid == 0) {
                    float q = 0.f;
                    for (int k = 0; k < HIDDEN; ++k) q += b1_1[k] * w2_1[k];
                    bc1[0] = q + b2_1[0];
                }
            } else if (tid < 256) {
                int i = tid - 128;
                float s = 0.f;
#pragma unroll 8
                for (int k = 0; k < HIDDEN; ++k)
                    s += w1_1[i * HIDDEN + k] * w2_1[k];
                wc1[i] = s;
            }
        }
        return;
    }

    __shared__ int hist[NB];
    __shared__ int lcur[NB];
    __shared__ int gbase[NB];

    if (tid < NB) { hist[tid] = 0; lcur[tid] = 0; }
    __syncthreads();

    unsigned mypk[4];
    short    myb[4];
    myb[0] = myb[1] = myb[2] = myb[3] = -1;

    if (tid < I4PB) {
        int i4 = bid * I4PB + tid;
        int e  = i4 << 2;
        if (e < N_EDGES) {                           // 1.6M % 4 == 0: all-or-none
            int4 s4 = reinterpret_cast<const int4*>(esrc)[i4];
            int4 d4 = reinterpret_cast<const int4*>(edst)[i4];
            int srcs[4] = { s4.x, s4.y, s4.z, s4.w };
            int dsts[4] = { d4.x, d4.y, d4.z, d4.w };
#pragma unroll
            for (int j = 0; j < 4; ++j) {
                int dst = dsts[j];
                int src = srcs[j];
                int b   = (int)(((unsigned long long)dst * MAGIC196) >> 38);
                int dl  = dst - b * NPB;             // 0..195 (8 bits)
                int vix = x_idx[src];                // 0..27  (5 bits)
                mypk[j] = ((unsigned)dl << 22) | ((unsigned)vix << 17) | (unsigned)src;
                myb[j]  = (short)b;
                atomicAdd(&hist[b], 1);
            }
        }
    }
    __syncthreads();

    if (tid < NB) {
        int v = hist[tid];
        gbase[tid] = (v > 0) ? atomicAdd(&gcursor[tid], v) : 0;
    }
    __syncthreads();

#pragma unroll
    for (int j = 0; j < 4; ++j) {
        if (myb[j] >= 0) {
            int b  = myb[j];
            int lr = atomicAdd(&lcur[b], 1);
            binned[(size_t)b * CAP + gbase[b] + lr] = mypk[j];
        }
    }
}

// ---------------------------------------------------------------------------
// k_layerC: one block (1024 thr) per bucket of 196 nodes; 22.7 KB LDS ->
// 2 blocks/CU.
//   1) uint4 scan of bucket edges -> LDS vocab histogram (stride-29)
//   2) epilogue on tid<NPB ONLY, with loop-variable-only indexing so ALL
//      EW/bc0/wc1 addresses are provably thread-invariant -> s_load_dwordx4.
//      (r8 lesson: q=tid>>8-derived indices forced per-lane vector loads +
//      VALU addr calc -> 64 us. Do NOT re-introduce thread-derived indices.)
//   dvec[n] = dot(relu(sum_v cf_v*EW[v] + bc0), wc1)
// ---------------------------------------------------------------------------
__global__ __launch_bounds__(1024) void k_layerC(const unsigned* __restrict__ binned,
                                                 const int* __restrict__ gcursor,
                                                 const int* __restrict__ x_idx,
                                                 const float* __restrict__ EW,
                                                 const float* __restrict__ bc0,
                                                 const float* __restrict__ wc1,
                                                 const float* __restrict__ eps0,
                                                 float* __restrict__ dvec) {
    __shared__ int lcnt[NPB * CSTR];    // 22.7 KB

    const int tid = threadIdx.x;
    const int b   = blockIdx.x;

    for (int i = tid; i < NPB * CSTR; i += 1024) lcnt[i] = 0;
    __syncthreads();

    const int cnt = gcursor[b];
    const unsigned* bp = binned + (size_t)b * CAP;
    const uint4* bp4 = reinterpret_cast<const uint4*>(bp);
    const int cnt4 = cnt >> 2;
    for (int i = tid; i < cnt4; i += 1024) {
        uint4 p = bp4[i];
        atomicAdd(&lcnt[(p.x >> 22) * CSTR + ((p.x >> 17) & 31)], 1);
        atomicAdd(&lcnt[(p.y >> 22) * CSTR + ((p.y >> 17) & 31)], 1);
        atomicAdd(&lcnt[(p.z >> 22) * CSTR + ((p.z >> 17) & 31)], 1);
        atomicAdd(&lcnt[(p.w >> 22) * CSTR + ((p.w >> 17) & 31)], 1);
    }
    for (int i = (cnt4 << 2) + tid; i < cnt; i += 1024) {   // tail < 4
        unsigned pk = bp[i];
        atomicAdd(&lcnt[(pk >> 22) * CSTR + ((pk >> 17) & 31)], 1);
    }
    __syncthreads();

    if (tid >= NPB) return;

    const int n      = b * NPB + tid;
    const bool valid = (n < N_NODES);
    const int xi     = valid ? x_idx[n] : 0;
    const float s    = 1.0f + eps0[0];

    float cf[VOCAB];
#pragma unroll
    for (int v = 0; v < VOCAB; ++v)
        cf[v] = (float)lcnt[tid * CSTR + v] + ((v == xi) ? s : 0.0f);

    const float4* EW4 = reinterpret_cast<const float4*>(EW);   // uniform -> s_load
    const float4* b04 = reinterpret_cast<const float4*>(bc0);
    const float4* w14 = reinterpret_cast<const float4*>(wc1);

    float dacc = 0.f;
#pragma unroll 1
    for (int f4 = 0; f4 < 32; ++f4) {
        float4 a = b04[f4];
#pragma unroll
        for (int v = 0; v < VOCAB; ++v) {
            float4 e = EW4[v * 32 + f4];
            a.x += cf[v] * e.x;
            a.y += cf[v] * e.y;
            a.z += cf[v] * e.z;
            a.w += cf[v] * e.w;
        }
        float4 w = w14[f4];
        dacc += fmaxf(a.x, 0.f) * w.x + fmaxf(a.y, 0.f) * w.y
              + fmaxf(a.z, 0.f) * w.z + fmaxf(a.w, 0.f) * w.w;
    }
    if (valid) dvec[n] = dacc;
}

// ---------------------------------------------------------------------------
// k_B2: one block (1024 thr) per bucket; ~9 KB LDS. uint4 scan; layer-1
// aggregation via LDS float atomics on racc[196] from L2-resident dvec
// gathers. Fused x write + graph segment-sum (batch sorted). OOB-clamped.
// ---------------------------------------------------------------------------
__global__ __launch_bounds__(1024) void k_B2(const unsigned* __restrict__ binned,
                                             const int* __restrict__ gcursor,
                                             const float* __restrict__ dvec,
                                             const int* __restrict__ batch,
                                             const float* __restrict__ eps1,
                                             const float* __restrict__ bc1,
                                             float* __restrict__ out) {
    __shared__ float racc[NPB];
    __shared__ float gacc[N_GRAPHS];

    const int tid = threadIdx.x;
    const int b   = blockIdx.x;
    const int n0  = b * NPB;
    const int nfirst = min(n0, N_NODES - 1);             // bucket 511: n0 >= N
    const int nlast  = min(n0 + NPB - 1, N_NODES - 1);

    if (tid < NPB) racc[tid] = 0.f;
    const int g0 = batch[nfirst];
    const int g1 = batch[nlast];
    for (int g = g0 + tid; g <= g1; g += 1024) gacc[g] = 0.f;
    __syncthreads();

    const int cnt = gcursor[b];
    const unsigned* bp = binned + (size_t)b * CAP;
    const uint4* bp4 = reinterpret_cast<const uint4*>(bp);
    const int cnt4 = cnt >> 2;
    for (int i = tid; i < cnt4; i += 1024) {
        uint4 p = bp4[i];
        atomicAdd(&racc[p.x >> 22], dvec[p.x & 0x1FFFFu]);
        atomicAdd(&racc[p.y >> 22], dvec[p.y & 0x1FFFFu]);
        atomicAdd(&racc[p.z >> 22], dvec[p.z & 0x1FFFFu]);
        atomicAdd(&racc[p.w >> 22], dvec[p.w & 0x1FFFFu]);
    }
    for (int i = (cnt4 << 2) + tid; i < cnt; i += 1024) {   // tail < 4
        unsigned pk = bp[i];
        atomicAdd(&racc[pk >> 22], dvec[pk & 0x1FFFFu]);
    }
    __syncthreads();

    int n = n0 + tid;
    if (tid < NPB && n < N_NODES) {
        float r = (1.0f + eps1[0]) * dvec[n] + racc[tid] + bc1[0];
        out[N_GRAPHS + n] = r;
        atomicAdd(&gacc[batch[n]], r);
    }
    __syncthreads();
    for (int g = g0 + tid; g <= g1; g += 1024) {
        float v = gacc[g];
        if (v != 0.f) atomicAdd(&out[g], v);
    }
}

// ---------------------------------------------------------------------------
extern "C" void kernel_launch(void* const* d_in, const int* in_sizes, int n_in,
                              void* d_out, int out_size, void* d_ws, size_t ws_size,
                              hipStream_t stream) {
    const int*   x_idx = (const int*)d_in[0];
    const int*   esrc  = (const int*)d_in[1];
    const int*   edst  = (const int*)d_in[2];
    const int*   batch = (const int*)d_in[3];
    const float* embed = (const float*)d_in[4];
    const float* eps0  = (const float*)d_in[5];
    const float* w1_0  = (const float*)d_in[6];
    const float* b1_0  = (const float*)d_in[7];
    const float* w2_0  = (const float*)d_in[8];
    const float* b2_0  = (const float*)d_in[9];
    const float* eps1  = (const float*)d_in[10];
    const float* w1_1  = (const float*)d_in[11];
    const float* b1_1  = (const float*)d_in[12];
    const float* w2_1  = (const float*)d_in[13];
    const float* b2_1  = (const float*)d_in[14];

    float* out = (float*)d_out;

    // ws: [gcursor(512) | binned(NB*CAP) | dvec(100352) | T | EW | bc0 | wc1 | bc1]
    int*      gcursor = (int*)d_ws;                           // 512
    unsigned* binned  = (unsigned*)(gcursor + 512);           // 512*3600
    float*    dvec    = (float*)(binned + (size_t)NB * CAP);  // 100352
    float*    T       = dvec + 100352;                        // 3584
    float*    EW      = T + VOCAB * HIDDEN;                   // 3584
    float*    bc0     = EW + VOCAB * HIDDEN;                  // 128
    float*    wc1     = bc0 + HIDDEN;                         // 128
    float*    bc1     = wc1 + HIDDEN;                         // 1

    // zero y_hat+gcursor; T = embed @ w1_0
    k_init<<<24, 256, 0, stream>>>(out, gcursor, embed, w1_0, T);

    // bin edges (int4 loads, 2 blocks/CU); EW/bias folds in extra blocks
    k_bin<<<NBIN + 5, 1024, 0, stream>>>(esrc, edst, x_idx, binned, gcursor,
                                         T, w2_0, b1_0, b2_0,
                                         w1_1, b1_1, w2_1, b2_1,
                                         EW, bc0, wc1, bc1);

    // layer 0 (+dot wc1): uint4 scan + uniform s_load FMA epilogue
    k_layerC<<<NB, 1024, 0, stream>>>(binned, gcursor, x_idx, EW, bc0, wc1,
                                      eps0, dvec);

    // layer 1 aggregation + fused outputs: uint4 scan
    k_B2<<<NB, 1024, 0, stream>>>(binned, gcursor, dvec, batch, eps1, bc1, out);
}